// Round 13
// baseline (76.052 us; speedup 1.0000x reference)
//
#include <hip/hip_runtime.h>

// LiftSplatShoot: out(B,N,3+C,H,W,D) = concat(world, feats_broadcast)
// B=4 N=6 C=80 H=16 W=44 D=59 -> 82,739,712 fp32 (~331 MB). Write-bound.
// Round 13: r11 (63.0us winner) + ONE change: XCD-chunked work swizzle on
// feature blocks. b2 -> chunk (b2&7)*247 + (b2>>3) (bijective, 1976=8*247):
// each XCD's 247 blocks start on 247 CONSECUTIVE chunks, so blocks sharing
// feats cache lines live on the SAME XCD L2 (r11 round-robin fetched each
// source line into up to 8 XCD L2s). Global moving front unchanged (~8MB).

#define BB 4
#define NN 6
#define CC 80
#define HH 16
#define WW 44
#define DD 59
#define BN (BB*NN)        // 24
#define PP (HH*WW)        // 704
#define CHO (CC+3)        // 83
#define DSTEP (0.9f/58.f)
#define Q4S 10384u        // float4s per slab (41536/4)
#define NFS 1920u         // feature slabs (24*80)
#define NFF4 (NFS*Q4S)    // feature float4s = 19,937,280
#define WBLK 72           // world blocks
#define FBLK 1976         // feature blocks (72+1976 = 2048 = 8/CU exact)

typedef float fx4 __attribute__((ext_vector_type(4)));
typedef unsigned int uint;

__device__ inline float waveMax(float v) {
#pragma unroll
    for (int o = 32; o; o >>= 1) v = fmaxf(v, __shfl_xor(v, o));
    return v;
}
__device__ inline float waveSum(float v) {
#pragma unroll
    for (int o = 32; o; o >>= 1) v += __shfl_xor(v, o);
    return v;
}

__global__ __launch_bounds__(256) void lss_fused(const float* __restrict__ feats,
                                                 const float* __restrict__ intr,
                                                 const float* __restrict__ extr,
                                                 float* __restrict__ out) {
    const int blk = blockIdx.x;
    const int tid = threadIdx.x;

    __shared__ float sf[PP];
    __shared__ float vw[PP + 1];
    __shared__ float sred[4];
    __shared__ float sbc[2];

    if (blk < WBLK) {
        // ---------------- world slab: bn = blk/3, ch = blk%3 ----------------
        const int bn = blk / 3;
        const int ch = blk - 3 * bn;

        // softmax of channel 79 into sf
        const float* f = feats + ((size_t)bn * CC + (CC - 1)) * PP;
        float m = -1e30f;
        for (int p = tid; p < PP; p += 256) { float v = f[p]; sf[p] = v; m = fmaxf(m, v); }
        m = waveMax(m);
        if ((tid & 63) == 0) sred[tid >> 6] = m;
        __syncthreads();
        if (tid == 0) sbc[0] = fmaxf(fmaxf(sred[0], sred[1]), fmaxf(sred[2], sred[3]));
        __syncthreads();
        const float mm = sbc[0];
        float s = 0.f;
        for (int p = tid; p < PP; p += 256) { float e = expf(sf[p] - mm); sf[p] = e; s += e; }
        s = waveSum(s);
        if ((tid & 63) == 0) sred[tid >> 6] = s;
        __syncthreads();
        if (tid == 0) sbc[1] = sred[0] + sred[1] + sred[2] + sred[3];
        __syncthreads();
        const float inv = 1.0f / sbc[1];

        // row ch of M = R*K^-1 (uniform)
        const float* K = intr + bn * 16;
        float a = K[0], b = K[1], c = K[2];
        float d = K[4], e = K[5], ff = K[6];
        float g = K[8], h9 = K[9], i9 = K[10];
        float det = a * (e * i9 - ff * h9) - b * (d * i9 - ff * g) + c * (d * h9 - e * g);
        float id = 1.0f / det;
        float kinv[9] = {
            (e * i9 - ff * h9) * id, (c * h9 - b * i9) * id, (b * ff - c * e) * id,
            (ff * g - d * i9) * id,  (a * i9 - c * g) * id,  (c * d - a * ff) * id,
            (d * h9 - e * g) * id,   (b * g - a * h9) * id,  (a * e - b * d) * id
        };
        const float* E = extr + bn * 16;
        float M0 = E[ch * 4 + 0] * kinv[0] + E[ch * 4 + 1] * kinv[3] + E[ch * 4 + 2] * kinv[6];
        float M1 = E[ch * 4 + 0] * kinv[1] + E[ch * 4 + 1] * kinv[4] + E[ch * 4 + 2] * kinv[7];
        float M2 = E[ch * 4 + 0] * kinv[2] + E[ch * 4 + 1] * kinv[5] + E[ch * 4 + 2] * kinv[8];
        const float T = E[ch * 4 + 3];

        for (int p = tid; p < PP; p += 256) {
            int hl = p / WW;
            int w  = p - hl * WW;
            float ray = M0 * (float)w + M1 * (float)hl + M2;
            vw[p] = ray * sf[p] * inv;
        }
        if (tid == 0) vw[PP] = 0.f;
        __syncthreads();

        // write the slab: out float4s [s*Q4S, (s+1)*Q4S)
        const uint s0 = (uint)(bn * CHO + ch) * Q4S;
        for (uint q = tid; q < Q4S; q += 256u) {
            uint c4 = q << 2;
            uint p  = c4 / 59u;
            uint d0 = c4 - 59u * p;
            uint kc = 59u - d0;              // first k using p+1 (>=4 if none)
            uint cw = (kc < 4u) ? 1u : 0u;
            float vA = vw[p];
            float vB = vw[p + cw];
            fx4 r;
#pragma unroll
            for (int k = 0; k < 4; ++k) {
                bool cr = ((uint)k >= kc);
                float val = cr ? vB : vA;
                uint dk = d0 + (uint)k - (cr ? 59u : 0u);
                r[k] = val * (0.1f + (float)dk * DSTEP) + T;
            }
            ((fx4*)out)[s0 + q] = r;
        }
    } else {
        // ---------------- feature slabs: XCD-chunked flat sweep ----------------
        // dispatch id (72+b2) -> XCD (b2 & 7). Swizzle start chunk so each
        // XCD owns 247 consecutive start positions: work = (b2&7)*247 + b2/8.
        const uint b2   = (uint)(blk - WBLK);              // 0..1975
        const uint work = (b2 & 7u) * 247u + (b2 >> 3);    // bijective [0,1976)
        const uint stride = FBLK * 256u;
        for (uint g = work * 256u + (uint)tid; g < NFF4; g += stride) {
            uint fs = g / Q4S;              // feature slab [0,1920)
            uint r4 = g - fs * Q4S;         // float4 within slab
            uint c4 = r4 << 2;
            uint p  = c4 / 59u;
            uint d0 = c4 - 59u * p;
            uint bn = fs / 80u;
            uint chf = fs - 80u * bn;       // 0..79
            uint kc = 59u - d0;
            uint cw = (kc < 4u) ? 1u : 0u;

            const float* src = feats + ((size_t)bn * CC + chf) * PP;
            float vA = src[p];
            float vB = src[p + cw];
            fx4 r;
#pragma unroll
            for (int k = 0; k < 4; ++k) r[k] = ((uint)k >= kc) ? vB : vA;

            uint s = bn * (uint)CHO + 3u + chf;   // output slab index
            ((fx4*)out)[s * Q4S + r4] = r;
        }
    }
}

extern "C" void kernel_launch(void* const* d_in, const int* in_sizes, int n_in,
                              void* d_out, int out_size, void* d_ws, size_t ws_size,
                              hipStream_t stream) {
    const float* feats = (const float*)d_in[0];
    const float* intr  = (const float*)d_in[1];
    const float* extr  = (const float*)d_in[2];
    float* out = (float*)d_out;

    lss_fused<<<WBLK + FBLK, 256, 0, stream>>>(feats, intr, extr, out);
}

// Round 14
// 66.239 us; speedup vs baseline: 1.1481x; 1.1481x over previous
//
#include <hip/hip_runtime.h>

// LiftSplatShoot: out(B,N,3+C,H,W,D) = concat(world, feats_broadcast)
// B=4 N=6 C=80 H=16 W=44 D=59 -> 82,739,712 fp32 (~331 MB). Write-bound.
// FINAL (= round 11 winner, 63.0us): single fused kernel.
//  - blocks 0..71: one world slab each (own softmax + M-row in LDS, write
//    166KB slab sequentially)
//  - blocks 72..2047: branch-free flat grid-stride over 1920 feature slabs
//    -> machine-wide coordinated contiguous write front (~8MB/step), dense
//    1KB-aligned wave bursts
//  - grid = 2048 blocks exactly = 8 blocks/CU on 256 CUs (no serialized tail)
// Falsified alternatives: NT stores (-17%), low occupancy (-2x), 32B/thread
// (-8%), per-block contiguous streams (-20%), XCD-chunked swizzle (-21%).

#define BB 4
#define NN 6
#define CC 80
#define HH 16
#define WW 44
#define DD 59
#define BN (BB*NN)        // 24
#define PP (HH*WW)        // 704
#define CHO (CC+3)        // 83
#define DSTEP (0.9f/58.f)
#define Q4S 10384u        // float4s per slab (41536/4)
#define NFS 1920u         // feature slabs (24*80)
#define NFF4 (NFS*Q4S)    // feature float4s = 19,937,280
#define WBLK 72           // world blocks
#define FBLK 1976         // feature blocks (72+1976 = 2048 = 8/CU exact)

typedef float fx4 __attribute__((ext_vector_type(4)));
typedef unsigned int uint;

__device__ inline float waveMax(float v) {
#pragma unroll
    for (int o = 32; o; o >>= 1) v = fmaxf(v, __shfl_xor(v, o));
    return v;
}
__device__ inline float waveSum(float v) {
#pragma unroll
    for (int o = 32; o; o >>= 1) v += __shfl_xor(v, o);
    return v;
}

__global__ __launch_bounds__(256) void lss_fused(const float* __restrict__ feats,
                                                 const float* __restrict__ intr,
                                                 const float* __restrict__ extr,
                                                 float* __restrict__ out) {
    const int blk = blockIdx.x;
    const int tid = threadIdx.x;

    __shared__ float sf[PP];
    __shared__ float vw[PP + 1];
    __shared__ float sred[4];
    __shared__ float sbc[2];

    if (blk < WBLK) {
        // ---------------- world slab: bn = blk/3, ch = blk%3 ----------------
        const int bn = blk / 3;
        const int ch = blk - 3 * bn;

        // softmax of channel 79 into sf
        const float* f = feats + ((size_t)bn * CC + (CC - 1)) * PP;
        float m = -1e30f;
        for (int p = tid; p < PP; p += 256) { float v = f[p]; sf[p] = v; m = fmaxf(m, v); }
        m = waveMax(m);
        if ((tid & 63) == 0) sred[tid >> 6] = m;
        __syncthreads();
        if (tid == 0) sbc[0] = fmaxf(fmaxf(sred[0], sred[1]), fmaxf(sred[2], sred[3]));
        __syncthreads();
        const float mm = sbc[0];
        float s = 0.f;
        for (int p = tid; p < PP; p += 256) { float e = expf(sf[p] - mm); sf[p] = e; s += e; }
        s = waveSum(s);
        if ((tid & 63) == 0) sred[tid >> 6] = s;
        __syncthreads();
        if (tid == 0) sbc[1] = sred[0] + sred[1] + sred[2] + sred[3];
        __syncthreads();
        const float inv = 1.0f / sbc[1];

        // row ch of M = R*K^-1 (uniform)
        const float* K = intr + bn * 16;
        float a = K[0], b = K[1], c = K[2];
        float d = K[4], e = K[5], ff = K[6];
        float g = K[8], h9 = K[9], i9 = K[10];
        float det = a * (e * i9 - ff * h9) - b * (d * i9 - ff * g) + c * (d * h9 - e * g);
        float id = 1.0f / det;
        float kinv[9] = {
            (e * i9 - ff * h9) * id, (c * h9 - b * i9) * id, (b * ff - c * e) * id,
            (ff * g - d * i9) * id,  (a * i9 - c * g) * id,  (c * d - a * ff) * id,
            (d * h9 - e * g) * id,   (b * g - a * h9) * id,  (a * e - b * d) * id
        };
        const float* E = extr + bn * 16;
        float M0 = E[ch * 4 + 0] * kinv[0] + E[ch * 4 + 1] * kinv[3] + E[ch * 4 + 2] * kinv[6];
        float M1 = E[ch * 4 + 0] * kinv[1] + E[ch * 4 + 1] * kinv[4] + E[ch * 4 + 2] * kinv[7];
        float M2 = E[ch * 4 + 0] * kinv[2] + E[ch * 4 + 1] * kinv[5] + E[ch * 4 + 2] * kinv[8];
        const float T = E[ch * 4 + 3];

        for (int p = tid; p < PP; p += 256) {
            int hl = p / WW;
            int w  = p - hl * WW;
            float ray = M0 * (float)w + M1 * (float)hl + M2;
            vw[p] = ray * sf[p] * inv;
        }
        if (tid == 0) vw[PP] = 0.f;
        __syncthreads();

        // write the slab: out float4s [s*Q4S, (s+1)*Q4S)
        const uint s0 = (uint)(bn * CHO + ch) * Q4S;
        for (uint q = tid; q < Q4S; q += 256u) {
            uint c4 = q << 2;
            uint p  = c4 / 59u;
            uint d0 = c4 - 59u * p;
            uint kc = 59u - d0;              // first k using p+1 (>=4 if none)
            uint cw = (kc < 4u) ? 1u : 0u;
            float vA = vw[p];
            float vB = vw[p + cw];
            fx4 r;
#pragma unroll
            for (int k = 0; k < 4; ++k) {
                bool cr = ((uint)k >= kc);
                float val = cr ? vB : vA;
                uint dk = d0 + (uint)k - (cr ? 59u : 0u);
                r[k] = val * (0.1f + (float)dk * DSTEP) + T;
            }
            ((fx4*)out)[s0 + q] = r;
        }
    } else {
        // ---------------- feature slabs: branch-free flat sweep ----------------
        const uint stride = FBLK * 256u;
        for (uint g = (uint)(blk - WBLK) * 256u + tid; g < NFF4; g += stride) {
            uint fs = g / Q4S;              // feature slab [0,1920)
            uint r4 = g - fs * Q4S;         // float4 within slab
            uint c4 = r4 << 2;
            uint p  = c4 / 59u;
            uint d0 = c4 - 59u * p;
            uint bn = fs / 80u;
            uint chf = fs - 80u * bn;       // 0..79
            uint kc = 59u - d0;
            uint cw = (kc < 4u) ? 1u : 0u;

            const float* src = feats + ((size_t)bn * CC + chf) * PP;
            float vA = src[p];
            float vB = src[p + cw];
            fx4 r;
#pragma unroll
            for (int k = 0; k < 4; ++k) r[k] = ((uint)k >= kc) ? vB : vA;

            uint s = bn * (uint)CHO + 3u + chf;   // output slab index
            ((fx4*)out)[s * Q4S + r4] = r;
        }
    }
}

extern "C" void kernel_launch(void* const* d_in, const int* in_sizes, int n_in,
                              void* d_out, int out_size, void* d_ws, size_t ws_size,
                              hipStream_t stream) {
    const float* feats = (const float*)d_in[0];
    const float* intr  = (const float*)d_in[1];
    const float* extr  = (const float*)d_in[2];
    float* out = (float*)d_out;

    lss_fused<<<WBLK + FBLK, 256, 0, stream>>>(feats, intr, extr, out);
}